// Round 1
// baseline (477.820 us; speedup 1.0000x reference)
//
#include <hip/hip_runtime.h>
#include <hip/hip_bf16.h>
#include <math.h>

// AttentionWithBias: B=4, N=1024, d=1024, H=16, hd=64
// All GEMMs in bf16 MFMA (16x16x32), fp32 accumulate, fp32 softmax+bias.

typedef __bf16 bf16;
typedef bf16 bf16x8 __attribute__((ext_vector_type(8)));
typedef bf16 bf16x4 __attribute__((ext_vector_type(4)));
typedef float floatx4 __attribute__((ext_vector_type(4)));

#define MFMA16(a, b, c) __builtin_amdgcn_mfma_f32_16x16x32_bf16((a), (b), (c), 0, 0, 0)

__device__ __forceinline__ void gload_lds16(const bf16* g, bf16* l) {
  // async global->LDS, 16B per lane; LDS dest = wave-uniform base + lane*16
  __builtin_amdgcn_global_load_lds(
      (const __attribute__((address_space(1))) unsigned int*)g,
      (__attribute__((address_space(3))) unsigned int*)l, 16, 0, 0);
}

// ---------------------------------------------------------------- convert
// dst layout (contiguous bf16): [x 4194304][Wq 1048576][Wk][Wv][Wo]
__global__ __launch_bounds__(256) void cvt_kernel(
    const float* __restrict__ x, const float* __restrict__ wq,
    const float* __restrict__ wk, const float* __restrict__ wv,
    const float* __restrict__ wo, bf16* __restrict__ dst) {
  long e = ((long)blockIdx.x * 256 + threadIdx.x) * 4;
  const float* src;
  if (e < 4194304) {
    src = x + e;
  } else {
    long r = (e - 4194304) >> 20;
    long off = (e - 4194304) & 1048575;
    src = (r == 0 ? wq : r == 1 ? wk : r == 2 ? wv : wo) + off;
  }
  float4 v = *reinterpret_cast<const float4*>(src);
  bf16x4 o = { (bf16)v.x, (bf16)v.y, (bf16)v.z, (bf16)v.w };
  *reinterpret_cast<bf16x4*>(dst + e) = o;
}

// ---------------------------------------------------------------- GEMM core
// C[128x128] = A[128x1024] . B[128x1024]^T  (both k-contiguous), m97 structure
__device__ __forceinline__ void gemm_mainloop(const bf16* __restrict__ Ag,
                                              const bf16* __restrict__ Bg,
                                              bf16* As, bf16* Bs,
                                              floatx4 acc[4][4]) {
  int tid = threadIdx.x;
  int w = tid >> 6, l = tid & 63, g = l >> 4, ln = l & 15;
  int wr = (w >> 1) << 6, wc = (w & 1) << 6;
  int lrow = w * 16 + (l >> 2);
  int lkc = (l & 3) * 8;
  for (int k0 = 0; k0 < 1024; k0 += 32) {
    __syncthreads();
    gload_lds16(Ag + (size_t)lrow * 1024 + k0 + lkc, As + w * 512);
    gload_lds16(Ag + (size_t)(lrow + 64) * 1024 + k0 + lkc, As + 2048 + w * 512);
    gload_lds16(Bg + (size_t)lrow * 1024 + k0 + lkc, Bs + w * 512);
    gload_lds16(Bg + (size_t)(lrow + 64) * 1024 + k0 + lkc, Bs + 2048 + w * 512);
    asm volatile("s_waitcnt vmcnt(0)" ::: "memory");
    __syncthreads();
    bf16x8 af[4], bfv[4];
#pragma unroll
    for (int t = 0; t < 4; t++) {
      af[t] = *(const bf16x8*)&As[(wr + t * 16 + ln) * 32 + g * 8];
      bfv[t] = *(const bf16x8*)&Bs[(wc + t * 16 + ln) * 32 + g * 8];
    }
#pragma unroll
    for (int i = 0; i < 4; i++)
#pragma unroll
      for (int j = 0; j < 4; j++)
        acc[i][j] = MFMA16(af[i], bfv[j], acc[i][j]);
  }
}

// ---------------------------------------------------------------- QKV projection
// z selects Wq/Wk/Wv; output scattered to [B,H,N,64] bf16
__global__ __launch_bounds__(256) void qkv_proj(
    const bf16* __restrict__ xb, const bf16* __restrict__ wqkv,
    bf16* __restrict__ Qo, bf16* __restrict__ Ko, bf16* __restrict__ Vo) {
  __shared__ bf16 As[4096], Bs[4096];
  const floatx4 z4 = {0.f, 0.f, 0.f, 0.f};
  floatx4 acc[4][4];
#pragma unroll
  for (int i = 0; i < 4; i++)
#pragma unroll
    for (int j = 0; j < 4; j++) acc[i][j] = z4;
  int z = blockIdx.z;
  const bf16* Ag = xb + (size_t)blockIdx.x * 128 * 1024;
  const bf16* Bg = wqkv + (size_t)z * 1048576 + (size_t)blockIdx.y * 128 * 1024;
  gemm_mainloop(Ag, Bg, As, Bs, acc);
  bf16* dst = z == 0 ? Qo : (z == 1 ? Ko : Vo);
  int tid = threadIdx.x, w = tid >> 6, l = tid & 63, g = l >> 4, ln = l & 15;
  int mbase = blockIdx.x * 128 + ((w >> 1) << 6);
  int ibase = blockIdx.y * 128 + ((w & 1) << 6);
#pragma unroll
  for (int i = 0; i < 4; i++)
#pragma unroll
    for (int j = 0; j < 4; j++)
#pragma unroll
      for (int r = 0; r < 4; r++) {
        int m = mbase + i * 16 + g * 4 + r;       // C/D layout: row=(l>>4)*4+reg
        int col = ibase + j * 16 + ln;            //            col=lane&15
        int b = m >> 10, n = m & 1023, h = col >> 6, di = col & 63;
        dst[((size_t)((b * 16 + h) * 1024 + n) << 6) + di] = (bf16)acc[i][j][r];
      }
}

// ---------------------------------------------------------------- flash attention
// grid: (16 q-tiles, 64 bh). Block 256 = 4 waves; wave handles 16 q-rows.
__global__ __launch_bounds__(256) void flash_kernel(
    const bf16* __restrict__ Q, const bf16* __restrict__ Kg,
    const bf16* __restrict__ Vg, const float* __restrict__ bias,
    bf16* __restrict__ Ao) {
  __shared__ bf16 Klds[64 * 72];      // [key][d], stride 72 (16B-aligned pad)
  __shared__ bf16 Vtlds[64 * 72];     // [d][key]
  __shared__ bf16 Plds[4 * 16 * 72];  // per-wave P [qrow][key]
  int tid = threadIdx.x;
  int w = tid >> 6, l = tid & 63, g = l >> 4, ln = l & 15;
  int qt = blockIdx.x;   // 0..15
  int bh = blockIdx.y;   // 0..63
  size_t bhN = (size_t)bh * 1024;

  // Q fragments (A-layout: m=lane&15, k=(lane>>4)*8+j), held for whole block
  const bf16* qptr = Q + (bhN + qt * 64 + w * 16 + ln) * 64;
  bf16x8 qf0 = *(const bf16x8*)(qptr + g * 8);
  bf16x8 qf1 = *(const bf16x8*)(qptr + 32 + g * 8);

  const floatx4 z4 = {0.f, 0.f, 0.f, 0.f};
  floatx4 o[4];
  float m_i[4], l_i[4];
#pragma unroll
  for (int i = 0; i < 4; i++) { o[i] = z4; m_i[i] = -1e30f; l_i[i] = 0.f; }

  // bias base for this lane: rows (4g+r), cols (t*16+ln)
  const float* bbase = bias + ((bhN + qt * 64 + w * 16 + g * 4) << 10) + ln;
  bf16* pw = Plds + w * 16 * 72;

  for (int kb = 0; kb < 16; kb++) {
    __syncthreads();
    // stage K tile [64x64] and transposed V tile; coalesced 16B global reads
#pragma unroll
    for (int c0 = 0; c0 < 2; c0++) {
      int c = c0 * 256 + tid;
      int key = c >> 3, kc = c & 7;
      const bf16* kp = Kg + (bhN + kb * 64 + key) * 64 + kc * 8;
      *(bf16x8*)&Klds[key * 72 + kc * 8] = *(const bf16x8*)kp;
      bf16x8 vv = *(const bf16x8*)(Vg + (bhN + kb * 64 + key) * 64 + kc * 8);
#pragma unroll
      for (int j = 0; j < 8; j++) Vtlds[(kc * 8 + j) * 72 + key] = vv[j];
    }
    __syncthreads();

    // S = Q K^T  (S tile t covers keys t*16..t*16+15)
    floatx4 s[4];
#pragma unroll
    for (int t = 0; t < 4; t++) {
      s[t] = z4;
      bf16x8 kf0 = *(const bf16x8*)&Klds[(t * 16 + ln) * 72 + g * 8];
      bf16x8 kf1 = *(const bf16x8*)&Klds[(t * 16 + ln) * 72 + 32 + g * 8];
      s[t] = MFMA16(qf0, kf0, s[t]);
      s[t] = MFMA16(qf1, kf1, s[t]);
    }
    // scale + bias (fp32, coalesced 64B segments per 16-lane group)
    const float* bp = bbase + kb * 64;
#pragma unroll
    for (int t = 0; t < 4; t++)
#pragma unroll
      for (int r = 0; r < 4; r++)
        s[t][r] = fmaf(s[t][r], 0.125f, bp[(size_t)r * 1024 + t * 16]);

    // online softmax: rows 4g+r live in lanes g*16..g*16+15
    float cmax[4], rs[4], alpha[4];
#pragma unroll
    for (int r = 0; r < 4; r++)
      cmax[r] = fmaxf(fmaxf(s[0][r], s[1][r]), fmaxf(s[2][r], s[3][r]));
#pragma unroll
    for (int mk = 1; mk < 16; mk <<= 1)
#pragma unroll
      for (int r = 0; r < 4; r++)
        cmax[r] = fmaxf(cmax[r], __shfl_xor(cmax[r], mk, 64));
#pragma unroll
    for (int r = 0; r < 4; r++) {
      float mn = fmaxf(m_i[r], cmax[r]);
      alpha[r] = __expf(m_i[r] - mn);
      m_i[r] = mn;
      rs[r] = 0.f;
    }
#pragma unroll
    for (int t = 0; t < 4; t++)
#pragma unroll
      for (int r = 0; r < 4; r++) {
        float p = __expf(s[t][r] - m_i[r]);
        s[t][r] = p;
        rs[r] += p;
      }
#pragma unroll
    for (int mk = 1; mk < 16; mk <<= 1)
#pragma unroll
      for (int r = 0; r < 4; r++) rs[r] += __shfl_xor(rs[r], mk, 64);
#pragma unroll
    for (int r = 0; r < 4; r++) l_i[r] = l_i[r] * alpha[r] + rs[r];
#pragma unroll
    for (int dt = 0; dt < 4; dt++)
#pragma unroll
      for (int r = 0; r < 4; r++) o[dt][r] *= alpha[r];

    // P: C-layout -> LDS (bf16) -> A-layout frags (per-wave private region)
#pragma unroll
    for (int t = 0; t < 4; t++)
#pragma unroll
      for (int r = 0; r < 4; r++)
        pw[(g * 4 + r) * 72 + t * 16 + ln] = (bf16)s[t][r];
    asm volatile("s_waitcnt lgkmcnt(0)" ::: "memory");  // wave-local LDS visibility

    bf16x8 pf0 = *(const bf16x8*)&pw[ln * 72 + g * 8];
    bf16x8 pf1 = *(const bf16x8*)&pw[ln * 72 + 32 + g * 8];
#pragma unroll
    for (int dt = 0; dt < 4; dt++) {
      bf16x8 vf0 = *(const bf16x8*)&Vtlds[(dt * 16 + ln) * 72 + g * 8];
      bf16x8 vf1 = *(const bf16x8*)&Vtlds[(dt * 16 + ln) * 72 + 32 + g * 8];
      o[dt] = MFMA16(pf0, vf0, o[dt]);
      o[dt] = MFMA16(pf1, vf1, o[dt]);
    }
  }

  // epilogue: O /= l, write attn_out [B*N, 1024] bf16 at col h*64+d
  int b = bh >> 4, h = bh & 15;
#pragma unroll
  for (int r = 0; r < 4; r++) {
    float inv = 1.f / l_i[r];
    int row = b * 1024 + qt * 64 + w * 16 + g * 4 + r;
    bf16* op = Ao + (size_t)row * 1024 + h * 64 + ln;
#pragma unroll
    for (int dt = 0; dt < 4; dt++) op[dt * 16] = (bf16)(o[dt][r] * inv);
  }
}

// ---------------------------------------------------------------- output projection
__global__ __launch_bounds__(256) void out_proj(const bf16* __restrict__ Ab,
                                                const bf16* __restrict__ wob,
                                                float* __restrict__ C) {
  __shared__ bf16 As[4096], Bs[4096];
  const floatx4 z4 = {0.f, 0.f, 0.f, 0.f};
  floatx4 acc[4][4];
#pragma unroll
  for (int i = 0; i < 4; i++)
#pragma unroll
    for (int j = 0; j < 4; j++) acc[i][j] = z4;
  const bf16* Ag = Ab + (size_t)blockIdx.x * 128 * 1024;
  const bf16* Bg = wob + (size_t)blockIdx.y * 128 * 1024;
  gemm_mainloop(Ag, Bg, As, Bs, acc);
  int tid = threadIdx.x, w = tid >> 6, l = tid & 63, g = l >> 4, ln = l & 15;
  int mbase = blockIdx.x * 128 + ((w >> 1) << 6);
  int cbase = blockIdx.y * 128 + ((w & 1) << 6);
#pragma unroll
  for (int i = 0; i < 4; i++)
#pragma unroll
    for (int j = 0; j < 4; j++)
#pragma unroll
      for (int r = 0; r < 4; r++)
        C[(size_t)(mbase + i * 16 + g * 4 + r) * 1024 + cbase + j * 16 + ln] =
            acc[i][j][r];
}

// ---------------------------------------------------------------- launch
extern "C" void kernel_launch(void* const* d_in, const int* in_sizes, int n_in,
                              void* d_out, int out_size, void* d_ws, size_t ws_size,
                              hipStream_t stream) {
  const float* x = (const float*)d_in[0];
  const float* bias = (const float*)d_in[1];
  const float* Wq = (const float*)d_in[2];
  const float* Wk = (const float*)d_in[3];
  const float* Wv = (const float*)d_in[4];
  const float* Wo = (const float*)d_in[5];
  float* out = (float*)d_out;

  // workspace layout (bf16 elements), ~48 MB total
  bf16* xb = (bf16*)d_ws;            // 4194304
  bf16* wqkv = xb + 4194304;         // 3*1048576 (Wq,Wk,Wv)
  bf16* wob = wqkv + 3 * 1048576;    // 1048576
  bf16* Qb = wob + 1048576;          // 4194304  [B,H,N,64]
  bf16* Kb = Qb + 4194304;           // 4194304  [B,H,N,64]
  bf16* Vb = Kb + 4194304;           // 4194304  [B,H,N,64]
  bf16* Ao = Vb + 4194304;           // 4194304  [B*N, 1024]

  cvt_kernel<<<8192, 256, 0, stream>>>(x, Wq, Wk, Wv, Wo, xb);
  qkv_proj<<<dim3(32, 8, 3), 256, 0, stream>>>(xb, wqkv, Qb, Kb, Vb);
  flash_kernel<<<dim3(16, 64), 256, 0, stream>>>(Qb, Kb, Vb, bias, Ao);
  out_proj<<<dim3(32, 8), 256, 0, stream>>>(Ao, wob, out);
}